// Round 1
// baseline (34450.146 us; speedup 1.0000x reference)
//
#include <hip/hip_runtime.h>
#include <hip/hip_bf16.h>

// NCDE branch: B=128 rows, L=200 RK4(3/8) steps, C=32, H=128, M=256.
// 8 clusters x 16 rows; 32 blocks/cluster; block = 256 threads.
// Cross-block exchange via d_ws + per-cluster atomic barrier (agent scope).

#define AGENT __HIP_MEMORY_SCOPE_AGENT

__device__ __forceinline__ float ldA(const float* p) {
  return __hip_atomic_load(p, __ATOMIC_RELAXED, AGENT);
}
__device__ __forceinline__ void stA(float* p, float v) {
  __hip_atomic_store(p, v, __ATOMIC_RELAXED, AGENT);
}

struct Lds {
  float4 zins4[16][32];   // zin [16][128], xor-swizzled chunks
  float4 w1t4[8][32];     // W1 slice [128][8] transposed, xor-swizzled
  float  hs[16][256];     // full h for the cluster rows
  float  ds[16][32];      // d-vector for current stage
  float  kacc[16][4][32]; // G2 partial merge: [r][cc][col4] (bank-friendly)
  float  kout[16][4];     // k-slice (4 h per block)
  float  lnsum[16][16];
  float  lnsq[16][16];
  float  lnmv[16][2];
};

__global__ void __launch_bounds__(256) ncde_kernel(
    const float* __restrict__ coeffs, const float* __restrict__ W1,
    const float* __restrict__ b1, const float* __restrict__ W2,
    const float* __restrict__ b2, const float* __restrict__ Wz,
    const float* __restrict__ bz, const float* __restrict__ gam,
    const float* __restrict__ bet, float* __restrict__ out,
    float* __restrict__ ws)
{
  __shared__ Lds L;
  const int t  = threadIdx.x;
  const int cl = blockIdx.x & 7;    // cluster (XCD-friendly if %8 round-robin)
  const int jp = blockIdx.x >> 3;   // position in cluster, 0..31

  unsigned* bcnt = (unsigned*)ws + cl * 64;
  unsigned* bgen = bcnt + 1;
  float* kb = ws + 1024 + cl * (4 * 2048);             // kbuf[4][16][128]
  float* hb = ws + 1024 + 8 * 4 * 2048 + cl * 4096;    // hbuf[16][256]

  const int zrow = t >> 4;   // 0..15  (row owned for z state)
  const int zseg = t & 15;   // 8-float segment of that row
  const int brow = cl * 16 + zrow;

  // ---- W1 slice preload: w1t4[mj][hc^mj] = W1[4hc..4hc+4][jp*8+mj] ----
  {
    const int mj = t >> 5;   // 0..7
    const int hc = t & 31;   // 0..31
    float4 v;
    v.x = W1[(hc * 4 + 0) * 256 + jp * 8 + mj];
    v.y = W1[(hc * 4 + 1) * 256 + jp * 8 + mj];
    v.z = W1[(hc * 4 + 2) * 256 + jp * 8 + mj];
    v.w = W1[(hc * 4 + 3) * 256 + jp * 8 + mj];
    L.w1t4[mj][hc ^ mj] = v;
  }

  // ---- z0 = a[:,0] @ Wz + bz (each block computes its rows fully) ----
  float zr_[8];
  {
    const float* arow = coeffs + (size_t)brow * 25600;  // a at offset 0
    #pragma unroll
    for (int i = 0; i < 8; ++i) {
      int h = zseg * 8 + i;
      float acc = bz[h];
      for (int c = 0; c < 32; ++c) acc += arow[c] * Wz[c * 128 + h];
      zr_[i] = acc;
    }
  }

  auto cbar = [&]() {
    __syncthreads();  // drains vmcnt: all sc1 stores globally visible
    if (t == 0) {
      unsigned g = __hip_atomic_load(bgen, __ATOMIC_RELAXED, AGENT);
      unsigned a = __hip_atomic_fetch_add(bcnt, 1u, __ATOMIC_RELAXED, AGENT);
      if (a == 31u) {
        __hip_atomic_store(bcnt, 0u, __ATOMIC_RELAXED, AGENT);
        asm volatile("s_waitcnt vmcnt(0)" ::: "memory");  // reset before bump
        __hip_atomic_fetch_add(bgen, 1u, __ATOMIC_RELAXED, AGENT);
      } else {
        while (__hip_atomic_load(bgen, __ATOMIC_RELAXED, AGENT) == g)
          __builtin_amdgcn_s_sleep(1);
      }
    }
    __syncthreads();
  };

  auto stage = [&](int l, int s) {
    // -- phase 1: d vector for this stage --
    {
      int lidx; float f = 0.f; bool bonly = false;
      if (s == 0) { if (l == 0) { lidx = 0; bonly = true; } else { lidx = l - 1; f = 1.f; } }
      else if (s == 1) { lidx = l; f = 1.f / 3.f; }
      else if (s == 2) { lidx = l; f = 2.f / 3.f; }
      else             { lidx = l; f = 1.f; }
      #pragma unroll
      for (int q = 0; q < 2; ++q) {
        int v = t * 2 + q, r = v >> 5, c = v & 31;
        const float* cp = coeffs + (size_t)(cl * 16 + r) * 25600 + (size_t)lidx * 128;
        float bco = cp[32 + c];
        L.ds[r][c] = bonly ? bco : bco + (cp[64 + c] + cp[96 + c] * f) * f;
      }
    }
    // -- phase 2: zin build (stage-dependent combination of z and k's) --
    {
      float vals[8];
      #pragma unroll
      for (int i = 0; i < 8; ++i) {
        int idx = zrow * 128 + zseg * 8 + i;
        float zv = zr_[i];
        if (s == 1)      zv += (1.f / 3.f) * ldA(kb + 0 * 2048 + idx);
        else if (s == 2) zv += ldA(kb + 1 * 2048 + idx) - (1.f / 3.f) * ldA(kb + 0 * 2048 + idx);
        else if (s == 3) zv += ldA(kb + 0 * 2048 + idx) - ldA(kb + 1 * 2048 + idx)
                               + ldA(kb + 2 * 2048 + idx);
        vals[i] = zv;
      }
      int sw = (2 * zrow) & 31;
      L.zins4[zrow][(zseg * 2 + 0) ^ sw] = make_float4(vals[0], vals[1], vals[2], vals[3]);
      L.zins4[zrow][(zseg * 2 + 1) ^ sw] = make_float4(vals[4], vals[5], vals[6], vals[7]);
    }
    __syncthreads();
    // -- phase 3: G1 slice (h = relu(zin@W1+b1), 8 M-cols per block) --
    if (t < 128) {
      int r = t >> 3, mj = t & 7;
      int sw = (2 * r) & 31;
      float acc = 0.f;
      #pragma unroll 4
      for (int hc = 0; hc < 32; ++hc) {
        float4 z4 = L.zins4[r][hc ^ sw];
        float4 w4 = L.w1t4[mj][hc ^ mj];
        acc += z4.x * w4.x + z4.y * w4.y + z4.z * w4.z + z4.w * w4.w;
      }
      acc += b1[jp * 8 + mj];
      acc = fmaxf(acc, 0.f);
      stA(hb + r * 256 + jp * 8 + mj, acc);
    }
    cbar();
    // -- phase 4: gather full h into LDS; zero partial buffers --
    {
      float* hsf = &L.hs[0][0];
      #pragma unroll
      for (int q = 0; q < 16; ++q) {
        int i = q * 256 + t;
        hsf[i] = ldA(hb + i);
      }
      float4* kz = (float4*)&L.kacc[0][0][0];
      kz[t * 2 + 0] = make_float4(0.f, 0.f, 0.f, 0.f);
      kz[t * 2 + 1] = make_float4(0.f, 0.f, 0.f, 0.f);
      if (t < 64) L.kout[t >> 2][t & 3] = 0.f;
    }
    __syncthreads();
    // -- phase 5: G2 slice: thread = (col4, kq); 16 rows x 4 cols x K-slice 32 --
    {
      const int col4 = t & 31, kq = t >> 5;
      const float* w2b = W2 + (size_t)(kq * 32) * 4096 + jp * 128 + col4 * 4;
      float acc[16][4];
      #pragma unroll
      for (int r = 0; r < 16; ++r) { acc[r][0] = acc[r][1] = acc[r][2] = acc[r][3] = 0.f; }
      float4 n0 = *(const float4*)(w2b);
      float4 n1 = *(const float4*)(w2b + 4096);
      float4 n2 = *(const float4*)(w2b + 2 * 4096);
      float4 n3 = *(const float4*)(w2b + 3 * 4096);
      for (int mo = 0; mo < 8; ++mo) {
        float4 w0 = n0, w1v = n1, w2v = n2, w3v = n3;
        if (mo < 7) {
          const float* nb = w2b + (size_t)(mo + 1) * 4 * 4096;
          n0 = *(const float4*)(nb);
          n1 = *(const float4*)(nb + 4096);
          n2 = *(const float4*)(nb + 2 * 4096);
          n3 = *(const float4*)(nb + 3 * 4096);
        }
        #pragma unroll
        for (int r = 0; r < 16; ++r) {
          float4 h4 = *(const float4*)&L.hs[r][(kq * 8 + mo) * 4];
          acc[r][0] += h4.x * w0.x + h4.y * w1v.x + h4.z * w2v.x + h4.w * w3v.x;
          acc[r][1] += h4.x * w0.y + h4.y * w1v.y + h4.z * w2v.y + h4.w * w3v.y;
          acc[r][2] += h4.x * w0.z + h4.y * w1v.z + h4.z * w2v.z + h4.w * w3v.z;
          acc[r][3] += h4.x * w0.w + h4.y * w1v.w + h4.z * w2v.w + h4.w * w3v.w;
        }
      }
      #pragma unroll
      for (int r = 0; r < 16; ++r) {
        #pragma unroll
        for (int cc = 0; cc < 4; ++cc)
          atomicAdd(&L.kacc[r][cc][col4], acc[r][cc]);
      }
    }
    __syncthreads();
    // -- phase 7: bias + tanh + d-weight + c-reduce --
    {
      int e0 = t * 8;
      int r = e0 >> 7;
      int colb = e0 & 127;
      int hl = colb >> 5;
      float lsum = 0.f;
      #pragma unroll
      for (int i = 0; i < 8; ++i) {
        int col = colb + i;
        float pre = L.kacc[r][col & 3][col >> 2] + b2[jp * 128 + col];
        float ax = fabsf(pre);
        float e = __expf(-2.f * ax);
        float th = (1.f - e) * __builtin_amdgcn_rcpf(1.f + e);
        th = (pre < 0.f) ? -th : th;
        lsum += th * L.ds[r][col & 31];
      }
      atomicAdd(&L.kout[r][hl], lsum);
    }
    __syncthreads();
    // -- phase 8: publish k-slice (4 h-values) --
    if (t < 64) {
      int r = t >> 2, hl = t & 3;
      stA(kb + s * 2048 + r * 128 + jp * 4 + hl, L.kout[r][hl]);
    }
    cbar();
  };

  auto lnorm = [&](int w) {
    {
      const float* p = kb + zrow * 128 + zseg * 8;  // k1 == sd pre-LN
      float s0 = 0.f, q0 = 0.f;
      #pragma unroll
      for (int i = 0; i < 8; ++i) { float x = ldA(p + i); s0 += x; q0 += x * x; }
      L.lnsum[zrow][zseg] = s0; L.lnsq[zrow][zseg] = q0;
    }
    __syncthreads();
    if (t < 16) {
      float s0 = 0.f, q0 = 0.f;
      #pragma unroll
      for (int j = 0; j < 16; ++j) { s0 += L.lnsum[t][j]; q0 += L.lnsq[t][j]; }
      float mu = s0 * (1.f / 128.f);
      float var = q0 * (1.f / 128.f) - mu * mu;
      L.lnmv[t][0] = mu;
      L.lnmv[t][1] = rsqrtf(var + 1e-5f);
    }
    __syncthreads();
    if (t < 64) {
      int r = t >> 2, hl = t & 3, h = jp * 4 + hl;
      float x = ldA(kb + r * 128 + h);
      float y = (x - L.lnmv[r][0]) * L.lnmv[r][1] * gam[h] + bet[h];
      y = fminf(fmaxf(y, -1000.f), 1000.f);
      out[(size_t)(cl * 16 + r) * 25728 + (size_t)w * 128 + h] = y;
    }
    __syncthreads();
  };

  for (int l = 0; l < 200; ++l) {
    stage(l, 0);
    lnorm(l);          // sd[:, l] == k1 of this step
    stage(l, 1);
    stage(l, 2);
    stage(l, 3);
    // z update: z += (k1 + 3(k2+k3) + k4)/8  (all k's published)
    #pragma unroll
    for (int i = 0; i < 8; ++i) {
      int idx = zrow * 128 + zseg * 8 + i;
      float k1 = ldA(kb + 0 * 2048 + idx);
      float k2 = ldA(kb + 1 * 2048 + idx);
      float k3 = ldA(kb + 2 * 2048 + idx);
      float k4 = ldA(kb + 3 * 2048 + idx);
      zr_[i] += 0.125f * (k1 + 3.f * (k2 + k3) + k4);
    }
  }
  stage(200, 0);   // field(z_L) . d_grid[:,200]
  lnorm(200);
}

extern "C" void kernel_launch(void* const* d_in, const int* in_sizes, int n_in,
                              void* d_out, int out_size, void* d_ws, size_t ws_size,
                              hipStream_t stream) {
  (void)in_sizes; (void)n_in; (void)out_size; (void)ws_size;
  const float* coeffs = (const float*)d_in[0];
  const float* W1     = (const float*)d_in[1];
  const float* b1     = (const float*)d_in[2];
  const float* W2     = (const float*)d_in[3];
  const float* b2     = (const float*)d_in[4];
  const float* Wz     = (const float*)d_in[5];
  const float* bz     = (const float*)d_in[6];
  const float* gam    = (const float*)d_in[7];
  const float* bet    = (const float*)d_in[8];
  float* out = (float*)d_out;
  float* ws  = (float*)d_ws;

  // barrier region (8 clusters x 256B) must start at 0 each launch
  hipMemsetAsync(d_ws, 0, 4096, stream);
  ncde_kernel<<<dim3(256), dim3(256), 0, stream>>>(coeffs, W1, b1, W2, b2, Wz, bz,
                                                   gam, bet, out, ws);
}

// Round 5
// 31764.996 us; speedup vs baseline: 1.0845x; 1.0845x over previous
//
#include <hip/hip_runtime.h>
#include <hip/hip_bf16.h>

// NCDE branch: B=128 rows, L=200 RK4(3/8) steps, C=32, H=128, M=256.
// 8 clusters x 16 rows; 32 blocks/cluster; block = 256 threads, 1 block/CU.
// Cross-block exchange via d_ws + per-cluster flag-array barrier (agent scope,
// no RMW contention: each block owns its arrival slot; leader ballots).

#define AGENT __HIP_MEMORY_SCOPE_AGENT

__device__ __forceinline__ float ldA(const float* p) {
  return __hip_atomic_load(p, __ATOMIC_RELAXED, AGENT);
}
__device__ __forceinline__ void stA(float* p, float v) {
  __hip_atomic_store(p, v, __ATOMIC_RELAXED, AGENT);
}

struct Lds {
  float4 zins4[16][32];   // zin [16][128], xor-swizzled chunks
  float4 w1t4[8][32];     // W1 slice [128][8] transposed, xor-swizzled
  float  hs[16][256];     // full h for the cluster rows
  float  ds[16][32];      // d-vector for current stage
  float  kacc[16][4][32]; // G2 partial merge: [r][cc][col4] (bank-friendly)
  float  kout[16][4];     // k-slice (4 h per block)
  float  lnsum[16][16];
  float  lnsq[16][16];
  float  lnmv[16][2];
};

__global__ void __launch_bounds__(256) ncde_kernel(
    const float* __restrict__ coeffs, const float* __restrict__ W1,
    const float* __restrict__ b1, const float* __restrict__ W2,
    const float* __restrict__ b2, const float* __restrict__ Wz,
    const float* __restrict__ bz, const float* __restrict__ gam,
    const float* __restrict__ bet, float* __restrict__ out,
    float* __restrict__ ws)
{
  __shared__ Lds L;
  const int t  = threadIdx.x;
  const int cl = blockIdx.x & 7;    // cluster (XCD-friendly if %8 round-robin)
  const int jp = blockIdx.x >> 3;   // position in cluster, 0..31

  // barrier area: per cluster 64 u32 (slots[32] + gen at [32])
  unsigned* slots = (unsigned*)ws + cl * 64;
  unsigned* genp  = slots + 32;
  unsigned  ph = 0;                 // monotone phase counter (per thread copy)

  float* kb = ws + 1024 + cl * (4 * 2048);             // kbuf[4][16][128]
  float* hb = ws + 1024 + 8 * 4 * 2048 + cl * 4096;    // hbuf[16][256]

  const int zrow = t >> 4;   // 0..15  (row owned for z state)
  const int zseg = t & 15;   // 8-float segment of that row
  const int brow = cl * 16 + zrow;

  // ---- W1 slice preload: w1t4[mj][hc^mj] = W1[4hc..4hc+4][jp*8+mj] ----
  {
    const int mj = t >> 5;   // 0..7
    const int hc = t & 31;   // 0..31
    float4 v;
    v.x = W1[(hc * 4 + 0) * 256 + jp * 8 + mj];
    v.y = W1[(hc * 4 + 1) * 256 + jp * 8 + mj];
    v.z = W1[(hc * 4 + 2) * 256 + jp * 8 + mj];
    v.w = W1[(hc * 4 + 3) * 256 + jp * 8 + mj];
    L.w1t4[mj][hc ^ mj] = v;
  }

  // ---- z0 = a[:,0] @ Wz + bz (each block computes its rows fully) ----
  float zr_[8];
  {
    const float* arow = coeffs + (size_t)brow * 25600;  // a at offset 0
    #pragma unroll
    for (int i = 0; i < 8; ++i) {
      int h = zseg * 8 + i;
      float acc = bz[h];
      for (int c = 0; c < 32; ++c) acc += arow[c] * Wz[c * 128 + h];
      zr_[i] = acc;
    }
  }

  // ---- contention-free cluster barrier ----
  // arrival: each block stores ph to its own slot (parallel, no RMW).
  // leader block (jp==0): lanes 0..31 poll the 32 slots; then bump gen.
  // followers: poll gen. All agent-scope (coherence point), monotone phases.
  auto cbar = [&]() {
    __syncthreads();   // drains vmcnt: all prior agent stores are visible
    ++ph;
    if (t == 0) __hip_atomic_store(&slots[jp], ph, __ATOMIC_RELAXED, AGENT);
    if (jp == 0) {
      if (t < 32) {
        while (__hip_atomic_load(&slots[t], __ATOMIC_RELAXED, AGENT) < ph)
          __builtin_amdgcn_s_sleep(2);
        if (t == 0) __hip_atomic_store(genp, ph, __ATOMIC_RELAXED, AGENT);
      }
    } else {
      if (t == 0) {
        while (__hip_atomic_load(genp, __ATOMIC_RELAXED, AGENT) < ph)
          __builtin_amdgcn_s_sleep(2);
      }
    }
    asm volatile("" ::: "memory");
    __syncthreads();
  };

  auto stage = [&](int l, int s) {
    // -- phase 1: d vector for this stage --
    {
      int lidx; float f = 0.f; bool bonly = false;
      if (s == 0) { if (l == 0) { lidx = 0; bonly = true; } else { lidx = l - 1; f = 1.f; } }
      else if (s == 1) { lidx = l; f = 1.f / 3.f; }
      else if (s == 2) { lidx = l; f = 2.f / 3.f; }
      else             { lidx = l; f = 1.f; }
      #pragma unroll
      for (int q = 0; q < 2; ++q) {
        int v = t * 2 + q, r = v >> 5, c = v & 31;
        const float* cp = coeffs + (size_t)(cl * 16 + r) * 25600 + (size_t)lidx * 128;
        float bco = cp[32 + c];
        L.ds[r][c] = bonly ? bco : bco + (cp[64 + c] + cp[96 + c] * f) * f;
      }
    }
    // -- phase 2: zin build (stage-dependent combination of z and k's) --
    {
      float vals[8];
      #pragma unroll
      for (int i = 0; i < 8; ++i) {
        int idx = zrow * 128 + zseg * 8 + i;
        float zv = zr_[i];
        if (s == 1)      zv += (1.f / 3.f) * ldA(kb + 0 * 2048 + idx);
        else if (s == 2) zv += ldA(kb + 1 * 2048 + idx) - (1.f / 3.f) * ldA(kb + 0 * 2048 + idx);
        else if (s == 3) zv += ldA(kb + 0 * 2048 + idx) - ldA(kb + 1 * 2048 + idx)
                               + ldA(kb + 2 * 2048 + idx);
        vals[i] = zv;
      }
      int sw = (2 * zrow) & 31;
      L.zins4[zrow][(zseg * 2 + 0) ^ sw] = make_float4(vals[0], vals[1], vals[2], vals[3]);
      L.zins4[zrow][(zseg * 2 + 1) ^ sw] = make_float4(vals[4], vals[5], vals[6], vals[7]);
    }
    __syncthreads();
    // -- phase 3: G1 slice (h = relu(zin@W1+b1), 8 M-cols per block) --
    if (t < 128) {
      int r = t >> 3, mj = t & 7;
      int sw = (2 * r) & 31;
      float acc = 0.f;
      #pragma unroll 4
      for (int hc = 0; hc < 32; ++hc) {
        float4 z4 = L.zins4[r][hc ^ sw];
        float4 w4 = L.w1t4[mj][hc ^ mj];
        acc += z4.x * w4.x + z4.y * w4.y + z4.z * w4.z + z4.w * w4.w;
      }
      acc += b1[jp * 8 + mj];
      acc = fmaxf(acc, 0.f);
      stA(hb + r * 256 + jp * 8 + mj, acc);
    }
    cbar();
    // -- phase 4: gather full h into LDS; zero partial buffers --
    {
      float* hsf = &L.hs[0][0];
      #pragma unroll
      for (int q = 0; q < 16; ++q) {
        int i = q * 256 + t;
        hsf[i] = ldA(hb + i);
      }
      float4* kz = (float4*)&L.kacc[0][0][0];
      kz[t * 2 + 0] = make_float4(0.f, 0.f, 0.f, 0.f);
      kz[t * 2 + 1] = make_float4(0.f, 0.f, 0.f, 0.f);
      if (t < 64) L.kout[t >> 2][t & 3] = 0.f;
    }
    __syncthreads();
    // -- phase 5: G2 slice: thread = (col4, kq); 16 rows x 4 cols x K-slice 32 --
    {
      const int col4 = t & 31, kq = t >> 5;
      const float* w2b = W2 + (size_t)(kq * 32) * 4096 + jp * 128 + col4 * 4;
      float acc[16][4];
      #pragma unroll
      for (int r = 0; r < 16; ++r) { acc[r][0] = acc[r][1] = acc[r][2] = acc[r][3] = 0.f; }
      float4 n0 = *(const float4*)(w2b);
      float4 n1 = *(const float4*)(w2b + 4096);
      float4 n2 = *(const float4*)(w2b + 2 * 4096);
      float4 n3 = *(const float4*)(w2b + 3 * 4096);
      for (int mo = 0; mo < 8; ++mo) {
        float4 w0 = n0, w1v = n1, w2v = n2, w3v = n3;
        if (mo < 7) {
          const float* nb = w2b + (size_t)(mo + 1) * 4 * 4096;
          n0 = *(const float4*)(nb);
          n1 = *(const float4*)(nb + 4096);
          n2 = *(const float4*)(nb + 2 * 4096);
          n3 = *(const float4*)(nb + 3 * 4096);
        }
        #pragma unroll
        for (int r = 0; r < 16; ++r) {
          float4 h4 = *(const float4*)&L.hs[r][(kq * 8 + mo) * 4];
          acc[r][0] += h4.x * w0.x + h4.y * w1v.x + h4.z * w2v.x + h4.w * w3v.x;
          acc[r][1] += h4.x * w0.y + h4.y * w1v.y + h4.z * w2v.y + h4.w * w3v.y;
          acc[r][2] += h4.x * w0.z + h4.y * w1v.z + h4.z * w2v.z + h4.w * w3v.z;
          acc[r][3] += h4.x * w0.w + h4.y * w1v.w + h4.z * w2v.w + h4.w * w3v.w;
        }
      }
      #pragma unroll
      for (int r = 0; r < 16; ++r) {
        #pragma unroll
        for (int cc = 0; cc < 4; ++cc)
          atomicAdd(&L.kacc[r][cc][col4], acc[r][cc]);
      }
    }
    __syncthreads();
    // -- phase 7: bias + tanh + d-weight + c-reduce --
    {
      int e0 = t * 8;
      int r = e0 >> 7;
      int colb = e0 & 127;
      int hl = colb >> 5;
      float lsum = 0.f;
      #pragma unroll
      for (int i = 0; i < 8; ++i) {
        int col = colb + i;
        float pre = L.kacc[r][col & 3][col >> 2] + b2[jp * 128 + col];
        float ax = fabsf(pre);
        float e = __expf(-2.f * ax);
        float th = (1.f - e) * __builtin_amdgcn_rcpf(1.f + e);
        th = (pre < 0.f) ? -th : th;
        lsum += th * L.ds[r][col & 31];
      }
      atomicAdd(&L.kout[r][hl], lsum);
    }
    __syncthreads();
    // -- phase 8: publish k-slice (4 h-values) --
    if (t < 64) {
      int r = t >> 2, hl = t & 3;
      stA(kb + s * 2048 + r * 128 + jp * 4 + hl, L.kout[r][hl]);
    }
    cbar();
  };

  auto lnorm = [&](int w) {
    {
      const float* p = kb + zrow * 128 + zseg * 8;  // k1 == sd pre-LN
      float s0 = 0.f, q0 = 0.f;
      #pragma unroll
      for (int i = 0; i < 8; ++i) { float x = ldA(p + i); s0 += x; q0 += x * x; }
      L.lnsum[zrow][zseg] = s0; L.lnsq[zrow][zseg] = q0;
    }
    __syncthreads();
    if (t < 16) {
      float s0 = 0.f, q0 = 0.f;
      #pragma unroll
      for (int j = 0; j < 16; ++j) { s0 += L.lnsum[t][j]; q0 += L.lnsq[t][j]; }
      float mu = s0 * (1.f / 128.f);
      float var = q0 * (1.f / 128.f) - mu * mu;
      L.lnmv[t][0] = mu;
      L.lnmv[t][1] = rsqrtf(var + 1e-5f);
    }
    __syncthreads();
    if (t < 64) {
      int r = t >> 2, hl = t & 3, h = jp * 4 + hl;
      float x = ldA(kb + r * 128 + h);
      float y = (x - L.lnmv[r][0]) * L.lnmv[r][1] * gam[h] + bet[h];
      y = fminf(fmaxf(y, -1000.f), 1000.f);
      out[(size_t)(cl * 16 + r) * 25728 + (size_t)w * 128 + h] = y;
    }
    __syncthreads();
  };

  for (int l = 0; l < 200; ++l) {
    stage(l, 0);
    lnorm(l);          // sd[:, l] == k1 of this step
    stage(l, 1);
    stage(l, 2);
    stage(l, 3);
    // z update: z += (k1 + 3(k2+k3) + k4)/8  (all k's published)
    #pragma unroll
    for (int i = 0; i < 8; ++i) {
      int idx = zrow * 128 + zseg * 8 + i;
      float k1 = ldA(kb + 0 * 2048 + idx);
      float k2 = ldA(kb + 1 * 2048 + idx);
      float k3 = ldA(kb + 2 * 2048 + idx);
      float k4 = ldA(kb + 3 * 2048 + idx);
      zr_[i] += 0.125f * (k1 + 3.f * (k2 + k3) + k4);
    }
  }
  stage(200, 0);   // field(z_L) . d_grid[:,200]
  lnorm(200);
}

extern "C" void kernel_launch(void* const* d_in, const int* in_sizes, int n_in,
                              void* d_out, int out_size, void* d_ws, size_t ws_size,
                              hipStream_t stream) {
  (void)in_sizes; (void)n_in; (void)out_size; (void)ws_size;
  const float* coeffs = (const float*)d_in[0];
  const float* W1     = (const float*)d_in[1];
  const float* b1     = (const float*)d_in[2];
  const float* W2     = (const float*)d_in[3];
  const float* b2     = (const float*)d_in[4];
  const float* Wz     = (const float*)d_in[5];
  const float* bz     = (const float*)d_in[6];
  const float* gam    = (const float*)d_in[7];
  const float* bet    = (const float*)d_in[8];
  float* out = (float*)d_out;
  float* ws  = (float*)d_ws;

  // barrier region (8 clusters x 256B of slots+gen) must start at 0 each launch
  hipMemsetAsync(d_ws, 0, 4096, stream);
  ncde_kernel<<<dim3(256), dim3(256), 0, stream>>>(coeffs, W1, b1, W2, b2, Wz, bz,
                                                   gam, bet, out, ws);
}

// Round 6
// 15802.034 us; speedup vs baseline: 2.1801x; 2.0102x over previous
//
#include <hip/hip_runtime.h>
#include <hip/hip_bf16.h>

// NCDE branch: B=128, L=200 RK4(3/8), C=32, H=128, M=256.
// 16 clusters x 8 rows; 32 blocks/cluster; grid 512, block 256 (2 blocks/CU).
// Clusters c and c+8 co-resident per CU (round-robin heuristic) -> barrier
// waits of one cluster hide under the other's compute. All cross-block bulk
// data moves as dwordx4 sc0 sc1 (MALL-coherent, 4x fewer transactions).

#define AGENT __HIP_MEMORY_SCOPE_AGENT

__device__ __forceinline__ float ldA(const float* p) {
  return __hip_atomic_load(p, __ATOMIC_RELAXED, AGENT);
}
__device__ __forceinline__ void stA(float* p, float v) {
  __hip_atomic_store(p, v, __ATOMIC_RELAXED, AGENT);
}
__device__ __forceinline__ float4 ld4A(const float* p) {
  float4 a;
  asm volatile("global_load_dwordx4 %0, %1, off sc0 sc1\n\t"
               "s_waitcnt vmcnt(0)"
               : "=v"(a) : "v"(p) : "memory");
  return a;
}
__device__ __forceinline__ void ld4A2(const float* p0, const float* p1,
                                      float4& a, float4& b) {
  asm volatile("global_load_dwordx4 %0, %2, off sc0 sc1\n\t"
               "global_load_dwordx4 %1, %3, off sc0 sc1\n\t"
               "s_waitcnt vmcnt(0)"
               : "=&v"(a), "=&v"(b) : "v"(p0), "v"(p1) : "memory");
}

struct Lds {
  float4 zins4[8][32];    // zin [8][128], xor-swizzled chunks (4KB)
  float4 w1t4[8][32];     // W1 slice [128][8] transposed, swizzled (4KB)
  float  hs[2048];        // full h, 8 rows x 256 (8KB)
  float  ds[8][32];       // d-vector for current stage (1KB)
  float  kacc2[8][1024];  // G2 partials [kq][r*128+cc*32+col4] (32KB, write-once)
  float  psum[8][32];     // phase-7 partials (1KB)
  float  kout[8][4];      // block's k slice
  float  lnsum[8][32];
  float  lnsq[8][32];
  float  lnmv[8][2];
};

__global__ void __launch_bounds__(256) ncde_kernel(
    const float* __restrict__ coeffs, const float* __restrict__ W1,
    const float* __restrict__ b1, const float* __restrict__ W2,
    const float* __restrict__ b2, const float* __restrict__ Wz,
    const float* __restrict__ bz, const float* __restrict__ gam,
    const float* __restrict__ bet, float* __restrict__ out,
    float* __restrict__ ws)
{
  __shared__ Lds L;
  const int t  = threadIdx.x;
  const int cl = blockIdx.x >> 5;   // 0..15 (clusters c, c+8 pair per CU)
  const int jp = blockIdx.x & 31;   // 0..31 (same-jp -> same XCD -> shared W2)

  unsigned* slots = (unsigned*)ws + cl * 64;   // 16 x 64 u32 = 4KB (memset 0)
  unsigned* genp  = slots + 32;
  unsigned  ph = 0;

  float* kb = ws + 1024 + cl * 4096;                 // [4][8][128] per cluster
  float* hb = ws + 1024 + 16 * 4096 + cl * 2048;     // [8][256] per cluster

  const int zrow = t >> 5;   // 0..7  owned row
  const int zseg = t & 31;   // 4-float segment
  const int brow = cl * 8 + zrow;

  // ---- W1 slice preload: w1t4[mj][hc^mj] = W1[4hc..][jp*8+mj] ----
  {
    const int mj = t >> 5, hc = t & 31;
    float4 v;
    v.x = W1[(hc * 4 + 0) * 256 + jp * 8 + mj];
    v.y = W1[(hc * 4 + 1) * 256 + jp * 8 + mj];
    v.z = W1[(hc * 4 + 2) * 256 + jp * 8 + mj];
    v.w = W1[(hc * 4 + 3) * 256 + jp * 8 + mj];
    L.w1t4[mj][hc ^ mj] = v;
  }

  // ---- z0 = a[:,0] @ Wz + bz ----
  float zr_[4];
  {
    const float* arow = coeffs + (size_t)brow * 25600;
    #pragma unroll
    for (int i = 0; i < 4; ++i) {
      int h = zseg * 4 + i;
      float acc = bz[h];
      for (int c = 0; c < 32; ++c) acc += arow[c] * Wz[c * 128 + h];
      zr_[i] = acc;
    }
  }

  // ---- contention-free cluster barrier (flag array + leader ballot) ----
  auto cbar = [&]() {
    __syncthreads();
    asm volatile("s_waitcnt vmcnt(0)" ::: "memory");  // drain asm sc1 stores
    ++ph;
    if (t == 0) __hip_atomic_store(&slots[jp], ph, __ATOMIC_RELAXED, AGENT);
    if (jp == 0) {
      if (t < 32) {
        while (__hip_atomic_load(&slots[t], __ATOMIC_RELAXED, AGENT) < ph)
          __builtin_amdgcn_s_sleep(1);
        if (t == 0) __hip_atomic_store(genp, ph, __ATOMIC_RELAXED, AGENT);
      }
    } else if (t == 0) {
      while (__hip_atomic_load(genp, __ATOMIC_RELAXED, AGENT) < ph)
        __builtin_amdgcn_s_sleep(1);
    }
    __syncthreads();
  };

  auto stage = [&](int l, int s) {
    // -- phase 1: d vector (thread = (zrow, zseg)) --
    {
      int lidx; float f = 0.f; bool bonly = false;
      if (s == 0) { if (l == 0) { lidx = 0; bonly = true; } else { lidx = l - 1; f = 1.f; } }
      else if (s == 1) { lidx = l; f = 1.f / 3.f; }
      else if (s == 2) { lidx = l; f = 2.f / 3.f; }
      else             { lidx = l; f = 1.f; }
      const float* cp = coeffs + (size_t)brow * 25600 + (size_t)lidx * 128;
      float bco = cp[32 + zseg];
      L.ds[zrow][zseg] = bonly ? bco : bco + (cp[64 + zseg] + cp[96 + zseg] * f) * f;
    }
    // -- phase 2: zin build --
    {
      int idx4 = zrow * 128 + zseg * 4;
      float4 zv = make_float4(zr_[0], zr_[1], zr_[2], zr_[3]);
      if (s == 1) {
        float4 k1 = ld4A(kb + idx4);
        zv.x += (1.f/3.f)*k1.x; zv.y += (1.f/3.f)*k1.y;
        zv.z += (1.f/3.f)*k1.z; zv.w += (1.f/3.f)*k1.w;
      } else if (s == 2) {
        float4 k1, k2; ld4A2(kb + idx4, kb + 1024 + idx4, k1, k2);
        zv.x += k2.x - (1.f/3.f)*k1.x; zv.y += k2.y - (1.f/3.f)*k1.y;
        zv.z += k2.z - (1.f/3.f)*k1.z; zv.w += k2.w - (1.f/3.f)*k1.w;
      } else if (s == 3) {
        float4 k1, k2; ld4A2(kb + idx4, kb + 1024 + idx4, k1, k2);
        float4 k3 = ld4A(kb + 2048 + idx4);
        zv.x += k1.x - k2.x + k3.x; zv.y += k1.y - k2.y + k3.y;
        zv.z += k1.z - k2.z + k3.z; zv.w += k1.w - k2.w + k3.w;
      }
      L.zins4[zrow][zseg ^ (zrow * 4)] = zv;
    }
    __syncthreads();
    // -- phase 3: G1 slice, 8 M-cols (64 threads) --
    if (t < 64) {
      int r = t >> 3, mj = t & 7;
      float acc = 0.f;
      #pragma unroll 8
      for (int hc = 0; hc < 32; ++hc) {
        float4 z4 = L.zins4[r][hc ^ (r * 4)];
        float4 w4 = L.w1t4[mj][hc ^ mj];
        acc += z4.x * w4.x + z4.y * w4.y + z4.z * w4.z + z4.w * w4.w;
      }
      acc += b1[jp * 8 + mj];
      acc = fmaxf(acc, 0.f);
      stA(hb + r * 256 + jp * 8 + mj, acc);
    }
    cbar();
    // -- phase 4: gather full h (2 x dwordx4 per thread, coalesced) --
    {
      float4 a, b;
      ld4A2(hb + t * 4, hb + 1024 + t * 4, a, b);
      *(float4*)&L.hs[t * 4] = a;
      *(float4*)&L.hs[1024 + t * 4] = b;
    }
    __syncthreads();
    // -- phase 5: G2 slice (thread = (col4, kq)); write-once partials --
    {
      const int col4 = t & 31, kq = t >> 5;
      const float* w2b = W2 + (size_t)(kq * 32) * 4096 + jp * 128 + col4 * 4;
      float4 acc[8];
      #pragma unroll
      for (int r = 0; r < 8; ++r) acc[r] = make_float4(0.f, 0.f, 0.f, 0.f);
      float4 n0 = *(const float4*)(w2b);
      float4 n1 = *(const float4*)(w2b + 4096);
      float4 n2 = *(const float4*)(w2b + 2 * 4096);
      float4 n3 = *(const float4*)(w2b + 3 * 4096);
      for (int mo = 0; mo < 8; ++mo) {
        float4 w0 = n0, w1v = n1, w2v = n2, w3v = n3;
        if (mo < 7) {
          const float* nb = w2b + (size_t)(mo + 1) * 4 * 4096;
          n0 = *(const float4*)(nb);
          n1 = *(const float4*)(nb + 4096);
          n2 = *(const float4*)(nb + 2 * 4096);
          n3 = *(const float4*)(nb + 3 * 4096);
        }
        #pragma unroll
        for (int r = 0; r < 8; ++r) {
          float4 h4 = *(const float4*)&L.hs[r * 256 + (kq * 8 + mo) * 4];
          acc[r].x += h4.x * w0.x + h4.y * w1v.x + h4.z * w2v.x + h4.w * w3v.x;
          acc[r].y += h4.x * w0.y + h4.y * w1v.y + h4.z * w2v.y + h4.w * w3v.y;
          acc[r].z += h4.x * w0.z + h4.y * w1v.z + h4.z * w2v.z + h4.w * w3v.z;
          acc[r].w += h4.x * w0.w + h4.y * w1v.w + h4.z * w2v.w + h4.w * w3v.w;
        }
      }
      #pragma unroll
      for (int r = 0; r < 8; ++r) {
        float* kp = &L.kacc2[kq][r * 128 + col4];
        kp[0] = acc[r].x; kp[32] = acc[r].y; kp[64] = acc[r].z; kp[96] = acc[r].w;
      }
    }
    __syncthreads();
    // -- phase 6: reduce partials over kq (vectorized, conflict-free) --
    {
      float4* k4p = (float4*)&L.kacc2[0][0];
      float4 sv = k4p[t];
      #pragma unroll
      for (int kq = 1; kq < 8; ++kq) {
        float4 v = k4p[kq * 256 + t];
        sv.x += v.x; sv.y += v.y; sv.z += v.z; sv.w += v.w;
      }
      k4p[t] = sv;
    }
    __syncthreads();
    // -- phase 7: bias + tanh + d-weight (thread = (r, g), 4 cols) --
    {
      int r = t >> 5, g = t & 31;
      float lsum = 0.f;
      #pragma unroll
      for (int i = 0; i < 4; ++i) {
        int col = g * 4 + i;
        float pre = L.kacc2[0][r * 128 + i * 32 + g] + b2[jp * 128 + col];
        float ax = fabsf(pre);
        float e = __expf(-2.f * ax);
        float th = (1.f - e) * __builtin_amdgcn_rcpf(1.f + e);
        th = (pre < 0.f) ? -th : th;
        lsum += th * L.ds[r][col & 31];
      }
      L.psum[r][g] = lsum;
    }
    __syncthreads();
    // -- phase 8: kout reduce + publish (t<32: r=t>>2, hl=t&3) --
    if (t < 32) {
      int r = t >> 2, hl = t & 3;
      float s0 = 0.f;
      #pragma unroll
      for (int g = 0; g < 8; ++g) s0 += L.psum[r][hl * 8 + g];
      L.kout[r][hl] = s0;
      stA(kb + s * 1024 + r * 128 + jp * 4 + hl, s0);
    }
    cbar();
  };

  auto lnorm = [&](int w) {
    {
      float4 v = ld4A(kb + zrow * 128 + zseg * 4);   // k1 == sd pre-LN
      L.lnsum[zrow][zseg] = v.x + v.y + v.z + v.w;
      L.lnsq[zrow][zseg]  = v.x*v.x + v.y*v.y + v.z*v.z + v.w*v.w;
    }
    __syncthreads();
    if (t < 8) {
      float s0 = 0.f, q0 = 0.f;
      #pragma unroll
      for (int j = 0; j < 32; ++j) { s0 += L.lnsum[t][j]; q0 += L.lnsq[t][j]; }
      float mu = s0 * (1.f / 128.f);
      float var = q0 * (1.f / 128.f) - mu * mu;
      L.lnmv[t][0] = mu;
      L.lnmv[t][1] = rsqrtf(var + 1e-5f);
    }
    __syncthreads();
    if (t < 32) {
      int r = t >> 2, hl = t & 3, h = jp * 4 + hl;
      float x = L.kout[r][hl];
      float y = (x - L.lnmv[r][0]) * L.lnmv[r][1] * gam[h] + bet[h];
      y = fminf(fmaxf(y, -1000.f), 1000.f);
      out[(size_t)(cl * 8 + r) * 25728 + (size_t)w * 128 + h] = y;
    }
    __syncthreads();
  };

  for (int l = 0; l < 200; ++l) {
    stage(l, 0);
    lnorm(l);
    stage(l, 1);
    stage(l, 2);
    stage(l, 3);
    {  // z += (k1 + 3(k2+k3) + k4)/8
      int idx4 = zrow * 128 + zseg * 4;
      float4 k1, k2, k3, k4;
      ld4A2(kb + idx4,        kb + 1024 + idx4, k1, k2);
      ld4A2(kb + 2048 + idx4, kb + 3072 + idx4, k3, k4);
      zr_[0] += 0.125f * (k1.x + 3.f * (k2.x + k3.x) + k4.x);
      zr_[1] += 0.125f * (k1.y + 3.f * (k2.y + k3.y) + k4.y);
      zr_[2] += 0.125f * (k1.z + 3.f * (k2.z + k3.z) + k4.z);
      zr_[3] += 0.125f * (k1.w + 3.f * (k2.w + k3.w) + k4.w);
    }
  }
  stage(200, 0);
  lnorm(200);
}

extern "C" void kernel_launch(void* const* d_in, const int* in_sizes, int n_in,
                              void* d_out, int out_size, void* d_ws, size_t ws_size,
                              hipStream_t stream) {
  (void)in_sizes; (void)n_in; (void)out_size; (void)ws_size;
  const float* coeffs = (const float*)d_in[0];
  const float* W1     = (const float*)d_in[1];
  const float* b1     = (const float*)d_in[2];
  const float* W2     = (const float*)d_in[3];
  const float* b2     = (const float*)d_in[4];
  const float* Wz     = (const float*)d_in[5];
  const float* bz     = (const float*)d_in[6];
  const float* gam    = (const float*)d_in[7];
  const float* bet    = (const float*)d_in[8];
  float* out = (float*)d_out;
  float* ws  = (float*)d_ws;

  // barrier region (16 clusters x 64 u32 = 4096B) must start at 0 each launch
  hipMemsetAsync(d_ws, 0, 4096, stream);
  ncde_kernel<<<dim3(512), dim3(256), 0, stream>>>(coeffs, W1, b1, W2, b2, Wz, bz,
                                                   gam, bet, out, ws);
}